// Round 3
// baseline (4746.484 us; speedup 1.0000x reference)
//
#include <hip/hip_runtime.h>

#define NPOINT 2048
#define NSAMPLE 32
#define NPTS 8192
#define NB 4
#define CH 16
#define FPS_THREADS 512
#define PTS_PER_THREAD (NPTS / FPS_THREADS) /* 16 */
#define FPS_WAVES (FPS_THREADS / 64)        /* 8 */

// Output layout (flat float32, concatenated in reference return order)
#define OFF_NEWXYZ 0
#define OFF_NEWPTS (NB * NPOINT * 3)                          /* 24576 */
#define OFF_IDX (OFF_NEWPTS + NB * NPOINT * NSAMPLE * CH)     /* 4218880 */
#define OFF_GXYZ (OFF_IDX + NB * NPOINT * NSAMPLE)            /* 4481024 */

// ---------------- FPS: one block per batch, sequential 2048-step scan ------
// Reference semantics: idxs[0]=0; each step: dists=min(dists,|p-p_last|^2),
// next = argmax(dists) with FIRST-index tie-break. Op order mirrored:
// (dx*dx + dy*dy) + dz*dz, no fma contraction.
//
// R1/R2 lesson: per-thread coord arrays (64 floats) spill to scratch
// (VGPR_Count 48/64, FETCH_SIZE ~1 GB = full state reload per iteration) and
// the launch_bounds min-waves hint did not raise the allocator's budget.
// Fix: coordinates live in LDS (96 KB of the CU's 160 KB); only d[16] stays
// in registers (~40 VGPRs total -> no spill possible at any allocator choice).
__global__ __launch_bounds__(FPS_THREADS) void fps_kernel(
    const float* __restrict__ in, float* __restrict__ out) {
  __shared__ float2 lpxy[NPTS];  // 64 KB, ds_read_b64, conflict-free
  __shared__ float lpz[NPTS];    // 32 KB, ds_read_b32, 2-way (free)
  // Double-buffered cross-wave reduction slots (parity = iteration & 1):
  // one __syncthreads per iteration.
  __shared__ float redv[2][FPS_WAVES];
  __shared__ int redi[2][FPS_WAVES];
  __shared__ float redx[2][FPS_WAVES], redy[2][FPS_WAVES], redz[2][FPS_WAVES];

  const int b = blockIdx.x;
  const int tid = threadIdx.x;
  const int lane = tid & 63;
  const int wv = tid >> 6;
  const float* base = in + (size_t)b * NPTS * CH;

  float d[PTS_PER_THREAD];
#pragma unroll
  for (int j = 0; j < PTS_PER_THREAD; ++j) {
    int p = tid + j * FPS_THREADS;
    float4 r = *reinterpret_cast<const float4*>(base + (size_t)p * CH);
    lpxy[p] = make_float2(r.x, r.y);
    lpz[p] = r.z;
    d[j] = __builtin_inff();
  }
  __syncthreads();
  // Prime buffer 0 with the initial selection: point 0 (value +inf wins).
  if (tid == 0) {
    redv[0][0] = __builtin_inff();
    redi[0][0] = 0;
    redx[0][0] = lpxy[0].x;
    redy[0][0] = lpxy[0].y;
    redz[0][0] = lpz[0];
#pragma unroll
    for (int w = 1; w < FPS_WAVES; ++w) {
      redv[0][w] = -1.0f;
      redi[0][w] = 0x40000000;
    }
  }

  for (int it = 0; it < NPOINT; ++it) {
    const int pb = it & 1;
    __syncthreads();
    // Every thread redundantly reduces the 8 wave leaders (identical result;
    // broadcast LDS reads are conflict-free).
    float gv = redv[pb][0];
    int gi = redi[pb][0];
    float gx = redx[pb][0], gy = redy[pb][0], gz = redz[pb][0];
#pragma unroll
    for (int w = 1; w < FPS_WAVES; ++w) {
      float v = redv[pb][w];
      int i = redi[pb][w];
      bool take = (v > gv) || (v == gv && i < gi);
      if (take) {
        gv = v;
        gi = i;
        gx = redx[pb][w];
        gy = redy[pb][w];
        gz = redz[pb][w];
      }
    }
    if (tid == 0) {
      float* o = out + OFF_NEWXYZ + ((size_t)b * NPOINT + it) * 3;
      o[0] = gx;
      o[1] = gy;
      o[2] = gz;
    }
    // Distance update + per-thread argmax (coords carried with the best).
    float bestv = -1.0f;
    int besti = 0;
    float bx = 0.f, by = 0.f, bz = 0.f;
#pragma unroll
    for (int j = 0; j < PTS_PER_THREAD; ++j) {
      int p = tid + j * FPS_THREADS;
      float2 xy = lpxy[p];
      float z = lpz[p];
      float dx = __fsub_rn(xy.x, gx);
      float dy = __fsub_rn(xy.y, gy);
      float dz = __fsub_rn(z, gz);
      float nd = __fadd_rn(__fadd_rn(__fmul_rn(dx, dx), __fmul_rn(dy, dy)),
                           __fmul_rn(dz, dz));
      float dn = fminf(d[j], nd);
      d[j] = dn;
      if (dn > bestv) {  // strict: keeps lowest j (= lowest index) on ties
        bestv = dn;
        besti = p;
        bx = xy.x;
        by = xy.y;
        bz = z;
      }
    }
    // Wave butterfly argmax, tie -> lowest index; coords ride along (the 5
    // shuffles per round are independent -> same 6-round latency).
#pragma unroll
    for (int off = 1; off < 64; off <<= 1) {
      float ov = __shfl_xor(bestv, off, 64);
      int oi = __shfl_xor(besti, off, 64);
      float ox = __shfl_xor(bx, off, 64);
      float oy = __shfl_xor(by, off, 64);
      float oz = __shfl_xor(bz, off, 64);
      if (ov > bestv || (ov == bestv && oi < besti)) {
        bestv = ov;
        besti = oi;
        bx = ox;
        by = oy;
        bz = oz;
      }
    }
    if (lane == 0) {
      redv[pb ^ 1][wv] = bestv;
      redi[pb ^ 1][wv] = besti;
      redx[pb ^ 1][wv] = bx;
      redy[pb ^ 1][wv] = by;
      redz[pb ^ 1][wv] = bz;
    }
  }
}

// ---------------- Ball query + group: one wave per query -------------------
__device__ __forceinline__ void write_slot(float* __restrict__ out,
                                           const float* __restrict__ base,
                                           int b, int qi, int s, int p,
                                           float4 r0, float qx, float qy,
                                           float qz) {
  float dx = __fsub_rn(r0.x, qx);
  float dy = __fsub_rn(r0.y, qy);
  float dz = __fsub_rn(r0.z, qz);
  size_t qs = (size_t)b * NPOINT + qi;
  out[OFF_IDX + qs * NSAMPLE + s] = (float)p;  // idx stored as float32
  float* g = out + OFF_GXYZ + (qs * NSAMPLE + s) * 3;
  g[0] = dx;
  g[1] = dy;
  g[2] = dz;
  const float* row = base + (size_t)p * CH;
  float4 r1 = *reinterpret_cast<const float4*>(row + 4);
  float4 r2 = *reinterpret_cast<const float4*>(row + 8);
  float4 r3 = *reinterpret_cast<const float4*>(row + 12);
  float* np_ = out + OFF_NEWPTS + (qs * NSAMPLE + s) * CH;
  *reinterpret_cast<float4*>(np_ + 0) = make_float4(dx, dy, dz, r0.w);
  *reinterpret_cast<float4*>(np_ + 4) = r1;
  *reinterpret_cast<float4*>(np_ + 8) = r2;
  *reinterpret_cast<float4*>(np_ + 12) = r3;
}

__global__ __launch_bounds__(256) void ballq_kernel(
    const float* __restrict__ in, float* __restrict__ out) {
  const int lane = threadIdx.x & 63;
  const int qid = blockIdx.x * 4 + (threadIdx.x >> 6);
  const int b = qid >> 11;    // / NPOINT
  const int qi = qid & 2047;  // % NPOINT
  const float* base = in + (size_t)b * NPTS * CH;
  const float* q = out + OFF_NEWXYZ + ((size_t)b * NPOINT + qi) * 3;
  float qx = q[0], qy = q[1], qz = q[2];
  // Mirror reference: d2 = sum(q*q) + sum(p*p) - 2*(q . p)
  float qn = __fadd_rn(__fadd_rn(__fmul_rn(qx, qx), __fmul_rn(qy, qy)),
                       __fmul_rn(qz, qz));

  int cnt = 0;
  int first = 0;
  bool have_first = false;
  for (int chunk = 0; chunk < NPTS / 64 && cnt < NSAMPLE; ++chunk) {
    int p = chunk * 64 + lane;
    float4 r0 = *reinterpret_cast<const float4*>(base + (size_t)p * CH);
    float pn =
        __fadd_rn(__fadd_rn(__fmul_rn(r0.x, r0.x), __fmul_rn(r0.y, r0.y)),
                  __fmul_rn(r0.z, r0.z));
    float dot =
        __fadd_rn(__fadd_rn(__fmul_rn(qx, r0.x), __fmul_rn(qy, r0.y)),
                  __fmul_rn(qz, r0.z));
    float d2 = __fsub_rn(__fadd_rn(qn, pn), __fmul_rn(2.0f, dot));
    bool in_r = d2 < 1.0f;  // RADIUS^2
    unsigned long long mask = __ballot(in_r);
    if (!have_first && mask) {
      first = chunk * 64 + __builtin_ctzll(mask);
      have_first = true;
    }
    int pos = cnt + __popcll(mask & ((1ull << lane) - 1ull));
    if (in_r && pos < NSAMPLE) write_slot(out, base, b, qi, pos, p, r0, qx, qy, qz);
    cnt += __popcll(mask);
  }
  if (cnt < NSAMPLE) {
    // Pad remaining slots with the first in-radius index (reference fill rule).
    int s = cnt + lane;
    if (s < NSAMPLE) {
      float4 r0 = *reinterpret_cast<const float4*>(base + (size_t)first * CH);
      write_slot(out, base, b, qi, s, first, r0, qx, qy, qz);
    }
  }
}

extern "C" void kernel_launch(void* const* d_in, const int* in_sizes, int n_in,
                              void* d_out, int out_size, void* d_ws,
                              size_t ws_size, hipStream_t stream) {
  (void)in_sizes;
  (void)n_in;
  (void)out_size;
  (void)d_ws;
  (void)ws_size;
  const float* in = (const float*)d_in[0];
  float* out = (float*)d_out;
  fps_kernel<<<NB, FPS_THREADS, 0, stream>>>(in, out);
  ballq_kernel<<<(NB * NPOINT) / 4, 256, 0, stream>>>(in, out);
}

// Round 4
// 2347.535 us; speedup vs baseline: 2.0219x; 2.0219x over previous
//
#include <hip/hip_runtime.h>

#define NPOINT 2048
#define NSAMPLE 32
#define NPTS 8192
#define NB 4
#define CH 16
#define FPS_THREADS 1024
#define PTS_PER_THREAD (NPTS / FPS_THREADS) /* 8 */
#define FPS_WAVES (FPS_THREADS / 64)        /* 16 */

typedef unsigned long long u64;

// Output layout (flat float32, concatenated in reference return order)
#define OFF_NEWXYZ 0
#define OFF_NEWPTS (NB * NPOINT * 3)                          /* 24576 */
#define OFF_IDX (OFF_NEWPTS + NB * NPOINT * NSAMPLE * CH)     /* 4218880 */
#define OFF_GXYZ (OFF_IDX + NB * NPOINT * NSAMPLE)            /* 4481024 */

// u64 argmax key: (float-bits of dist << 32) | (8191 - idx).
// dist >= 0 -> bits monotone; max key = max dist, tie -> lowest idx (exact
// jnp.argmax tie-break). Identity/fill value 0 never beats a real key.
template <int CTRL>
__device__ __forceinline__ u64 dpp_max_round(u64 key) {
  unsigned lo = (unsigned)key, hi = (unsigned)(key >> 32);
  unsigned plo =
      (unsigned)__builtin_amdgcn_update_dpp(0, (int)lo, CTRL, 0xf, 0xf, true);
  unsigned phi =
      (unsigned)__builtin_amdgcn_update_dpp(0, (int)hi, CTRL, 0xf, 0xf, true);
  u64 other = ((u64)phi << 32) | plo;
  return other > key ? other : key;
}

// ---------------- FPS: one block per batch, sequential 2048-step scan ------
// Reference semantics: idxs[0]=0; each step: dists=min(dists,|p-p_last|^2),
// next = argmax(dists) with FIRST-index tie-break. Op order mirrored:
// (dx*dx + dy*dy) + dz*dz, no fma contraction.
//
// R1-R3 lessons (FETCH_SIZE is KB! no spill ever happened):
//  - ds_bpermute shuffles (~30 cyc, LDS pipe) dominated the old butterfly ->
//    replaced with DPP rounds (VALU speed) on a single packed u64 key.
//  - global newxyz store per iter forced vmcnt(0) drain at the barrier ->
//    buffer in LDS, dump once at the end.
//  - LDS reads in the inner loop are slower than register arrays -> 8
//    pts/thread keeps state ~60 VGPRs (pure VGPR at any allocator choice).
__global__ __launch_bounds__(FPS_THREADS) void fps_kernel(
    const float* __restrict__ in, float* __restrict__ out) {
  __shared__ float2 lpxy[NPTS];          // 64 KB (winner-coord broadcast read)
  __shared__ float lpz[NPTS];            // 32 KB
  __shared__ float newb[NPOINT * 3];     // 24 KB newxyz staging
  __shared__ u64 slots[2][FPS_WAVES];    // parity double-buffered wave maxima

  const int b = blockIdx.x;
  const int tid = threadIdx.x;
  const int lane = tid & 63;
  const int wv = tid >> 6;
  const float* base = in + (size_t)b * NPTS * CH;

  float px[PTS_PER_THREAD], py[PTS_PER_THREAD], pz[PTS_PER_THREAD],
      d[PTS_PER_THREAD];
#pragma unroll
  for (int j = 0; j < PTS_PER_THREAD; ++j) {
    int p = tid + j * FPS_THREADS;
    float4 r = *reinterpret_cast<const float4*>(base + (size_t)p * CH);
    px[j] = r.x;
    py[j] = r.y;
    pz[j] = r.z;
    lpxy[p] = make_float2(r.x, r.y);
    lpz[p] = r.z;
    d[j] = __builtin_inff();
  }
  // Prime parity-0 slots: point 0 wins the first reduce (+inf dist bits).
  if (tid < FPS_WAVES)
    slots[0][tid] = (tid == 0) ? (((u64)0x7f800000u << 32) | 8191u) : 0ull;

  for (int it = 0; it < NPOINT; ++it) {
    const int pb = it & 1;
    __syncthreads();
    // Tree-reduce the 16 wave slots (every thread redundantly; broadcast LDS
    // reads are conflict-free; 4-level dep chain).
    u64 t[FPS_WAVES];
#pragma unroll
    for (int w = 0; w < FPS_WAVES; ++w) t[w] = slots[pb][w];
#pragma unroll
    for (int s = FPS_WAVES / 2; s > 0; s >>= 1)
#pragma unroll
      for (int w = 0; w < FPS_WAVES; ++w)
        if (w < s && t[w + s] > t[w]) t[w] = t[w + s];
    const int gi = 8191 - (int)(unsigned)(t[0] & 0xffffffffu);
    // Winner coords: broadcast LDS read.
    float2 gxy = lpxy[gi];
    float gz = lpz[gi];
    float gx = gxy.x, gy = gxy.y;
    if (tid == 0) {
      newb[it * 3 + 0] = gx;
      newb[it * 3 + 1] = gy;
      newb[it * 3 + 2] = gz;
    }
    // Distance update + packed-key argmax (register arrays, no LDS).
    u64 bestkey = 0;
    const unsigned lbase = 8191u - (unsigned)tid;
#pragma unroll
    for (int j = 0; j < PTS_PER_THREAD; ++j) {
      float dx = __fsub_rn(px[j], gx);
      float dy = __fsub_rn(py[j], gy);
      float dz = __fsub_rn(pz[j], gz);
      float nd = __fadd_rn(__fadd_rn(__fmul_rn(dx, dx), __fmul_rn(dy, dy)),
                           __fmul_rn(dz, dz));
      float dn = fminf(d[j], nd);
      d[j] = dn;
      u64 cand =
          ((u64)__float_as_uint(dn) << 32) | (lbase - (unsigned)(j * FPS_THREADS));
      if (cand > bestkey) bestkey = cand;
    }
    // Wave-level max via DPP (VALU speed; 0-fill is a valid identity).
    bestkey = dpp_max_round<0x111>(bestkey);  // row_shr:1
    bestkey = dpp_max_round<0x112>(bestkey);  // row_shr:2
    bestkey = dpp_max_round<0x114>(bestkey);  // row_shr:4
    bestkey = dpp_max_round<0x118>(bestkey);  // row_shr:8
    bestkey = dpp_max_round<0x142>(bestkey);  // row_bcast15
    bestkey = dpp_max_round<0x143>(bestkey);  // row_bcast31
    if (lane == 63) slots[pb ^ 1][wv] = bestkey;  // lane 63 holds wave max
  }
  __syncthreads();
  // Dump staged newxyz to global once.
  float* ob = out + OFF_NEWXYZ + (size_t)b * NPOINT * 3;
  for (int i = tid; i < NPOINT * 3; i += FPS_THREADS) ob[i] = newb[i];
}

// ---------------- Ball query + group: one wave per query -------------------
__device__ __forceinline__ void write_slot(float* __restrict__ out,
                                           const float* __restrict__ base,
                                           int b, int qi, int s, int p,
                                           float4 r0, float qx, float qy,
                                           float qz) {
  float dx = __fsub_rn(r0.x, qx);
  float dy = __fsub_rn(r0.y, qy);
  float dz = __fsub_rn(r0.z, qz);
  size_t qs = (size_t)b * NPOINT + qi;
  out[OFF_IDX + qs * NSAMPLE + s] = (float)p;  // idx stored as float32
  float* g = out + OFF_GXYZ + (qs * NSAMPLE + s) * 3;
  g[0] = dx;
  g[1] = dy;
  g[2] = dz;
  const float* row = base + (size_t)p * CH;
  float4 r1 = *reinterpret_cast<const float4*>(row + 4);
  float4 r2 = *reinterpret_cast<const float4*>(row + 8);
  float4 r3 = *reinterpret_cast<const float4*>(row + 12);
  float* np_ = out + OFF_NEWPTS + (qs * NSAMPLE + s) * CH;
  *reinterpret_cast<float4*>(np_ + 0) = make_float4(dx, dy, dz, r0.w);
  *reinterpret_cast<float4*>(np_ + 4) = r1;
  *reinterpret_cast<float4*>(np_ + 8) = r2;
  *reinterpret_cast<float4*>(np_ + 12) = r3;
}

__global__ __launch_bounds__(256) void ballq_kernel(
    const float* __restrict__ in, float* __restrict__ out) {
  const int lane = threadIdx.x & 63;
  const int qid = blockIdx.x * 4 + (threadIdx.x >> 6);
  const int b = qid >> 11;    // / NPOINT
  const int qi = qid & 2047;  // % NPOINT
  const float* base = in + (size_t)b * NPTS * CH;
  const float* q = out + OFF_NEWXYZ + ((size_t)b * NPOINT + qi) * 3;
  float qx = q[0], qy = q[1], qz = q[2];
  // Mirror reference: d2 = sum(q*q) + sum(p*p) - 2*(q . p)
  float qn = __fadd_rn(__fadd_rn(__fmul_rn(qx, qx), __fmul_rn(qy, qy)),
                       __fmul_rn(qz, qz));

  int cnt = 0;
  int first = 0;
  bool have_first = false;
  for (int chunk = 0; chunk < NPTS / 64 && cnt < NSAMPLE; ++chunk) {
    int p = chunk * 64 + lane;
    float4 r0 = *reinterpret_cast<const float4*>(base + (size_t)p * CH);
    float pn =
        __fadd_rn(__fadd_rn(__fmul_rn(r0.x, r0.x), __fmul_rn(r0.y, r0.y)),
                  __fmul_rn(r0.z, r0.z));
    float dot =
        __fadd_rn(__fadd_rn(__fmul_rn(qx, r0.x), __fmul_rn(qy, r0.y)),
                  __fmul_rn(qz, r0.z));
    float d2 = __fsub_rn(__fadd_rn(qn, pn), __fmul_rn(2.0f, dot));
    bool in_r = d2 < 1.0f;  // RADIUS^2
    unsigned long long mask = __ballot(in_r);
    if (!have_first && mask) {
      first = chunk * 64 + __builtin_ctzll(mask);
      have_first = true;
    }
    int pos = cnt + __popcll(mask & ((1ull << lane) - 1ull));
    if (in_r && pos < NSAMPLE) write_slot(out, base, b, qi, pos, p, r0, qx, qy, qz);
    cnt += __popcll(mask);
  }
  if (cnt < NSAMPLE) {
    // Pad remaining slots with the first in-radius index (reference fill rule).
    int s = cnt + lane;
    if (s < NSAMPLE) {
      float4 r0 = *reinterpret_cast<const float4*>(base + (size_t)first * CH);
      write_slot(out, base, b, qi, s, first, r0, qx, qy, qz);
    }
  }
}

extern "C" void kernel_launch(void* const* d_in, const int* in_sizes, int n_in,
                              void* d_out, int out_size, void* d_ws,
                              size_t ws_size, hipStream_t stream) {
  (void)in_sizes;
  (void)n_in;
  (void)out_size;
  (void)d_ws;
  (void)ws_size;
  const float* in = (const float*)d_in[0];
  float* out = (float*)d_out;
  fps_kernel<<<NB, FPS_THREADS, 0, stream>>>(in, out);
  ballq_kernel<<<(NB * NPOINT) / 4, 256, 0, stream>>>(in, out);
}

// Round 6
// 2167.208 us; speedup vs baseline: 2.1901x; 1.0832x over previous
//
#include <hip/hip_runtime.h>

#define NPOINT 2048
#define NSAMPLE 32
#define NPTS 8192
#define NB 4
#define CH 16
#define FPS_THREADS 1024
#define PTS_PER_THREAD (NPTS / FPS_THREADS) /* 8 */
#define FPS_WAVES (FPS_THREADS / 64)        /* 16 */

typedef unsigned long long u64;

// Output layout (flat float32, concatenated in reference return order)
#define OFF_NEWXYZ 0
#define OFF_NEWPTS (NB * NPOINT * 3)                          /* 24576 */
#define OFF_IDX (OFF_NEWPTS + NB * NPOINT * NSAMPLE * CH)     /* 4218880 */
#define OFF_GXYZ (OFF_IDX + NB * NPOINT * NSAMPLE)            /* 4481024 */

// u64 argmax key: (float-bits of dist << 32) | (8191 - idx).
// dist >= 0 -> bits monotone; max key = max dist, tie -> lowest idx (exact
// jnp.argmax tie-break). Identity/fill value 0 never beats a real key.
template <int CTRL>
__device__ __forceinline__ u64 dpp_max_round(u64 key) {
  unsigned lo = (unsigned)key, hi = (unsigned)(key >> 32);
  unsigned plo =
      (unsigned)__builtin_amdgcn_update_dpp(0, (int)lo, CTRL, 0xf, 0xf, true);
  unsigned phi =
      (unsigned)__builtin_amdgcn_update_dpp(0, (int)hi, CTRL, 0xf, 0xf, true);
  u64 other = ((u64)phi << 32) | plo;
  return other > key ? other : key;
}

// ---------------- FPS: one block per batch, sequential 2048-step scan ------
// Reference semantics: idxs[0]=0; each step: dists=min(dists,|p-p_last|^2),
// next = argmax(dists) with FIRST-index tie-break. Op order mirrored:
// (dx*dx + dy*dy) + dz*dz, no fma contraction (matches numpy/JAX rounding).
//
// R5 bug fixed here: DPP row_shr accumulates toward HIGHER lanes, so after
// the 4 rounds the 16-slot max lives in lane 15 (not lane 0). readfirstlane
// returned wave 0's local max -> wrong FPS trajectory. Use readlane(.., 15).
__global__ __launch_bounds__(FPS_THREADS) void fps_kernel(
    const float* __restrict__ in, float* __restrict__ out) {
  __shared__ float4 lpxyz[NPTS];       // 128 KB; winner coords: 1 ds_read_b128
  __shared__ float newb[NPOINT * 3];   // 24 KB newxyz staging
  __shared__ u64 slots[2][FPS_WAVES];  // parity double-buffered wave maxima

  const int b = blockIdx.x;
  const int tid = threadIdx.x;
  const int lane = tid & 63;
  const int wv = tid >> 6;
  const float* base = in + (size_t)b * NPTS * CH;

  float px[PTS_PER_THREAD], py[PTS_PER_THREAD], pz[PTS_PER_THREAD],
      d[PTS_PER_THREAD];
#pragma unroll
  for (int j = 0; j < PTS_PER_THREAD; ++j) {
    int p = tid + j * FPS_THREADS;
    float4 r = *reinterpret_cast<const float4*>(base + (size_t)p * CH);
    px[j] = r.x;
    py[j] = r.y;
    pz[j] = r.z;
    lpxyz[p] = r;
    d[j] = __builtin_inff();
  }
  // Prime parity-0 slots: point 0 wins the first reduce (+inf dist bits).
  if (tid < FPS_WAVES)
    slots[0][tid] = (tid == 0) ? (((u64)0x7f800000u << 32) | 8191u) : 0ull;

  for (int it = 0; it < NPOINT; ++it) {
    const int pb = it & 1;
    __syncthreads();
    // Lane-parallel cross-wave reduce: lane reads slots[lane&15] (2-way bank
    // aliasing = free), 4 DPP row_shr rounds -> lane 15 holds the max of all
    // 16 slots; readlane(15) broadcasts the index word to an SGPR.
    u64 k = slots[pb][lane & 15];
    k = dpp_max_round<0x111>(k);  // row_shr:1
    k = dpp_max_round<0x112>(k);  // row_shr:2
    k = dpp_max_round<0x114>(k);  // row_shr:4
    k = dpp_max_round<0x118>(k);  // row_shr:8
    const int gi =
        8191 -
        (int)(unsigned)__builtin_amdgcn_readlane((int)(unsigned)k, 15);
    // Winner coords: broadcast LDS read (uniform SGPR address).
    float4 g = lpxyz[gi];
    const float gx = g.x, gy = g.y, gz = g.z;
    if (tid == 0) {
      newb[it * 3 + 0] = gx;
      newb[it * 3 + 1] = gy;
      newb[it * 3 + 2] = gz;
    }
    // Distance update + per-thread argmax (val,j separate: 3 inst/pt; strict
    // '>' with ascending j keeps lowest index on ties).
    float bestv = -1.0f;
    int bestj = 0;
#pragma unroll
    for (int j = 0; j < PTS_PER_THREAD; ++j) {
      float dx = __fsub_rn(px[j], gx);
      float dy = __fsub_rn(py[j], gy);
      float dz = __fsub_rn(pz[j], gz);
      float nd = __fadd_rn(__fadd_rn(__fmul_rn(dx, dx), __fmul_rn(dy, dy)),
                           __fmul_rn(dz, dz));
      float dn = fminf(d[j], nd);
      d[j] = dn;
      if (dn > bestv) {
        bestv = dn;
        bestj = j;
      }
    }
    const int besti = tid + bestj * FPS_THREADS;
    u64 bestkey = ((u64)__float_as_uint(bestv) << 32) | (8191u - (unsigned)besti);
    // Wave-level max via DPP (VALU speed; 0-fill is a valid identity).
    // row_shr rounds push the max toward lane 63; bcast15/31 finish it.
    bestkey = dpp_max_round<0x111>(bestkey);  // row_shr:1
    bestkey = dpp_max_round<0x112>(bestkey);  // row_shr:2
    bestkey = dpp_max_round<0x114>(bestkey);  // row_shr:4
    bestkey = dpp_max_round<0x118>(bestkey);  // row_shr:8
    bestkey = dpp_max_round<0x142>(bestkey);  // row_bcast15
    bestkey = dpp_max_round<0x143>(bestkey);  // row_bcast31
    if (lane == 63) slots[pb ^ 1][wv] = bestkey;  // lane 63 holds wave max
  }
  __syncthreads();
  // Dump staged newxyz to global once.
  float* ob = out + OFF_NEWXYZ + (size_t)b * NPOINT * 3;
  for (int i = tid; i < NPOINT * 3; i += FPS_THREADS) ob[i] = newb[i];
}

// ---------------- Ball query + group: one wave per query -------------------
__device__ __forceinline__ void write_slot(float* __restrict__ out,
                                           const float* __restrict__ base,
                                           int b, int qi, int s, int p,
                                           float4 r0, float qx, float qy,
                                           float qz) {
  float dx = __fsub_rn(r0.x, qx);
  float dy = __fsub_rn(r0.y, qy);
  float dz = __fsub_rn(r0.z, qz);
  size_t qs = (size_t)b * NPOINT + qi;
  out[OFF_IDX + qs * NSAMPLE + s] = (float)p;  // idx stored as float32
  float* g = out + OFF_GXYZ + (qs * NSAMPLE + s) * 3;
  g[0] = dx;
  g[1] = dy;
  g[2] = dz;
  const float* row = base + (size_t)p * CH;
  float4 r1 = *reinterpret_cast<const float4*>(row + 4);
  float4 r2 = *reinterpret_cast<const float4*>(row + 8);
  float4 r3 = *reinterpret_cast<const float4*>(row + 12);
  float* np_ = out + OFF_NEWPTS + (qs * NSAMPLE + s) * CH;
  *reinterpret_cast<float4*>(np_ + 0) = make_float4(dx, dy, dz, r0.w);
  *reinterpret_cast<float4*>(np_ + 4) = r1;
  *reinterpret_cast<float4*>(np_ + 8) = r2;
  *reinterpret_cast<float4*>(np_ + 12) = r3;
}

__global__ __launch_bounds__(256) void ballq_kernel(
    const float* __restrict__ in, float* __restrict__ out) {
  const int lane = threadIdx.x & 63;
  const int qid = blockIdx.x * 4 + (threadIdx.x >> 6);
  const int b = qid >> 11;    // / NPOINT
  const int qi = qid & 2047;  // % NPOINT
  const float* base = in + (size_t)b * NPTS * CH;
  const float* q = out + OFF_NEWXYZ + ((size_t)b * NPOINT + qi) * 3;
  float qx = q[0], qy = q[1], qz = q[2];
  // Mirror reference: d2 = sum(q*q) + sum(p*p) - 2*(q . p)
  float qn = __fadd_rn(__fadd_rn(__fmul_rn(qx, qx), __fmul_rn(qy, qy)),
                       __fmul_rn(qz, qz));

  int cnt = 0;
  int first = 0;
  bool have_first = false;
  for (int chunk = 0; chunk < NPTS / 64 && cnt < NSAMPLE; ++chunk) {
    int p = chunk * 64 + lane;
    float4 r0 = *reinterpret_cast<const float4*>(base + (size_t)p * CH);
    float pn =
        __fadd_rn(__fadd_rn(__fmul_rn(r0.x, r0.x), __fmul_rn(r0.y, r0.y)),
                  __fmul_rn(r0.z, r0.z));
    float dot =
        __fadd_rn(__fadd_rn(__fmul_rn(qx, r0.x), __fmul_rn(qy, r0.y)),
                  __fmul_rn(qz, r0.z));
    float d2 = __fsub_rn(__fadd_rn(qn, pn), __fmul_rn(2.0f, dot));
    bool in_r = d2 < 1.0f;  // RADIUS^2
    unsigned long long mask = __ballot(in_r);
    if (!have_first && mask) {
      first = chunk * 64 + __builtin_ctzll(mask);
      have_first = true;
    }
    int pos = cnt + __popcll(mask & ((1ull << lane) - 1ull));
    if (in_r && pos < NSAMPLE) write_slot(out, base, b, qi, pos, p, r0, qx, qy, qz);
    cnt += __popcll(mask);
  }
  if (cnt < NSAMPLE) {
    // Pad remaining slots with the first in-radius index (reference fill rule).
    int s = cnt + lane;
    if (s < NSAMPLE) {
      float4 r0 = *reinterpret_cast<const float4*>(base + (size_t)first * CH);
      write_slot(out, base, b, qi, s, first, r0, qx, qy, qz);
    }
  }
}

extern "C" void kernel_launch(void* const* d_in, const int* in_sizes, int n_in,
                              void* d_out, int out_size, void* d_ws,
                              size_t ws_size, hipStream_t stream) {
  (void)in_sizes;
  (void)n_in;
  (void)out_size;
  (void)d_ws;
  (void)ws_size;
  const float* in = (const float*)d_in[0];
  float* out = (float*)d_out;
  fps_kernel<<<NB, FPS_THREADS, 0, stream>>>(in, out);
  ballq_kernel<<<(NB * NPOINT) / 4, 256, 0, stream>>>(in, out);
}

// Round 9
// 2028.930 us; speedup vs baseline: 2.3394x; 1.0682x over previous
//
#include <hip/hip_runtime.h>

// File-scope: forbid implicit fma contraction everywhere (keeps every a*b+c
// as two single-rounded IEEE ops, matching the numpy reference bit-for-bit;
// explicit __f*_rn intrinsics below are unaffected). At file scope this
// placement is unambiguously legal for clang.
#pragma clang fp contract(off)

#define NPOINT 2048
#define NSAMPLE 32
#define NPTS 8192
#define NB 4
#define CH 16
#define FPS_THREADS 1024
#define PTS_PER_THREAD (NPTS / FPS_THREADS) /* 8 */
#define PAIRS (PTS_PER_THREAD / 2)          /* 4 */
#define FPS_WAVES (FPS_THREADS / 64)        /* 16 */

typedef unsigned long long u64;
typedef float v2f __attribute__((ext_vector_type(2)));

// Output layout (flat float32, concatenated in reference return order)
#define OFF_NEWXYZ 0
#define OFF_NEWPTS (NB * NPOINT * 3)                          /* 24576 */
#define OFF_IDX (OFF_NEWPTS + NB * NPOINT * NSAMPLE * CH)     /* 4218880 */
#define OFF_GXYZ (OFF_IDX + NB * NPOINT * NSAMPLE)            /* 4481024 */

template <int CTRL>
__device__ __forceinline__ float dpp_fmax(float v) {
  // bound_ctrl=true -> 0-fill; distances are >= 0 so 0 is a safe identity.
  int o = __builtin_amdgcn_update_dpp(0, __float_as_int(v), CTRL, 0xf, 0xf, true);
  return fmaxf(v, __int_as_float(o));
}

// ---------------- FPS: one block per batch, sequential 2048-step scan ------
// Reference semantics: idxs[0]=0; each step: dists=min(dists,|p-p_last|^2),
// next = argmax(dists) with FIRST-index tie-break. Op order mirrored:
// (dx*dx + dy*dy) + dz*dz, single-rounded IEEE ops, no fma contraction
// (file-scope pragma). Packed v2f math has identical per-element rounding.
//
// R6 lesson: active CUs ~89% VALU-issue-busy -> cut instructions. u64
// (val,idx) keys are expensive (5 inst/DPP round); instead reduce f32 max
// only and recover the index by ballot + ctz. CONTIGUOUS ownership
// (thread t owns points t*8..t*8+7) makes (wave, lane, j) order == global
// index order, so lowest-set-lane / lowest-wave = lowest index (exact
// jnp.argmax tie-break).
__global__ __launch_bounds__(FPS_THREADS) void fps_kernel(
    const float* __restrict__ in, float* __restrict__ out) {
  __shared__ float4 lpxyz[NPTS];      // 128 KB; winner coords: 1 ds_read_b128
  __shared__ float newb[NPOINT * 3];  // 24 KB newxyz staging
  __shared__ u64 slots[2][FPS_WAVES]; // low=dist bits, high=idx (per wave)

  const int b = blockIdx.x;
  const int tid = threadIdx.x;
  const int lane = tid & 63;
  const int wv = tid >> 6;
  const float* base = in + (size_t)b * NPTS * CH;

  v2f pxv[PAIRS], pyv[PAIRS], pzv[PAIRS], dv[PAIRS];
#pragma unroll
  for (int jp = 0; jp < PAIRS; ++jp) {
    int p0 = tid * PTS_PER_THREAD + 2 * jp;
    float4 r0 = *reinterpret_cast<const float4*>(base + (size_t)p0 * CH);
    float4 r1 = *reinterpret_cast<const float4*>(base + (size_t)(p0 + 1) * CH);
    pxv[jp] = (v2f){r0.x, r1.x};
    pyv[jp] = (v2f){r0.y, r1.y};
    pzv[jp] = (v2f){r0.z, r1.z};
    lpxyz[p0] = r0;
    lpxyz[p0 + 1] = r1;
    dv[jp] = (v2f){__builtin_inff(), __builtin_inff()};
  }
  // Prime parity-0 slots: slot 0 = (+inf, idx 0) wins the first reduce.
  if (tid < FPS_WAVES)
    slots[0][tid] = (tid == 0) ? (u64)0x7f800000u : (u64)0xbf800000u;

  for (int it = 0; it < NPOINT; ++it) {
    const int pb = it & 1;
    __syncthreads();
    // Cross-wave reduce: lane reads slot[lane&15] (2-way bank alias = free);
    // 4 f32 DPP row_shr max rounds -> every row's lane 15 = max of 16 slots;
    // ballot(own==max)&0xFFFF, ctz -> lowest wave (= lowest index range).
    u64 sl = slots[pb][lane & 15];
    float sd = __int_as_float((int)(unsigned)sl);
    int sidx = (int)(unsigned)(sl >> 32);
    float m = sd;
    m = dpp_fmax<0x111>(m);  // row_shr:1
    m = dpp_fmax<0x112>(m);  // row_shr:2
    m = dpp_fmax<0x114>(m);  // row_shr:4
    m = dpp_fmax<0x118>(m);  // row_shr:8
    const float smax =
        __int_as_float(__builtin_amdgcn_readlane(__float_as_int(m), 15));
    const u64 bal = __ballot(sd == smax) & 0xFFFFull;
    const int wwin = (int)__builtin_ctzll(bal);
    const int gi = __builtin_amdgcn_readlane(sidx, wwin);
    // Winner coords: broadcast LDS read (uniform SGPR address).
    float4 g = lpxyz[gi];
    const float gx = g.x, gy = g.y, gz = g.z;
    if (tid == 0) {
      newb[it * 3 + 0] = gx;
      newb[it * 3 + 1] = gy;
      newb[it * 3 + 2] = gz;
    }
    // Distance update (packed pairs; exact IEEE per-element, no contraction)
    // + value-only max.
    float bestv = -1.0f;
#pragma unroll
    for (int jp = 0; jp < PAIRS; ++jp) {
      v2f dx = pxv[jp] - gx;
      v2f dy = pyv[jp] - gy;
      v2f dz = pzv[jp] - gz;
      v2f nd = (dx * dx + dy * dy) + dz * dz;
      v2f dn = {fminf(dv[jp].x, nd.x), fminf(dv[jp].y, nd.y)};
      dv[jp] = dn;
      bestv = fmaxf(bestv, fmaxf(dn.x, dn.y));
    }
    // Recover lowest j achieving bestv (descending scan -> lowest wins).
    const float* df = (const float*)dv;
    int bestj = 0;
#pragma unroll
    for (int jj = PTS_PER_THREAD - 1; jj >= 0; --jj)
      if (df[jj] == bestv) bestj = jj;
    const int besti = tid * PTS_PER_THREAD + bestj;
    // Wave reduce: f32 DPP max -> lane 63; ballot picks lowest lane (= lowest
    // index under contiguous ownership); readlane pulls its index.
    float wm = bestv;
    wm = dpp_fmax<0x111>(wm);  // row_shr:1
    wm = dpp_fmax<0x112>(wm);  // row_shr:2
    wm = dpp_fmax<0x114>(wm);  // row_shr:4
    wm = dpp_fmax<0x118>(wm);  // row_shr:8
    wm = dpp_fmax<0x142>(wm);  // row_bcast15
    wm = dpp_fmax<0x143>(wm);  // row_bcast31
    const float swm =
        __int_as_float(__builtin_amdgcn_readlane(__float_as_int(wm), 63));
    const u64 wbal = __ballot(bestv == swm);
    const int wl = (int)__builtin_ctzll(wbal);
    const int widx = __builtin_amdgcn_readlane(besti, wl);
    if (lane == 0)
      slots[pb ^ 1][wv] =
          ((u64)(unsigned)widx << 32) | (unsigned)__float_as_int(swm);
  }
  __syncthreads();
  // Dump staged newxyz to global once.
  float* ob = out + OFF_NEWXYZ + (size_t)b * NPOINT * 3;
  for (int i = tid; i < NPOINT * 3; i += FPS_THREADS) ob[i] = newb[i];
}

// ---------------- Ball query + group: one wave per query -------------------
__device__ __forceinline__ void write_slot(float* __restrict__ out,
                                           const float* __restrict__ base,
                                           int b, int qi, int s, int p,
                                           float4 r0, float qx, float qy,
                                           float qz) {
  float dx = __fsub_rn(r0.x, qx);
  float dy = __fsub_rn(r0.y, qy);
  float dz = __fsub_rn(r0.z, qz);
  size_t qs = (size_t)b * NPOINT + qi;
  out[OFF_IDX + qs * NSAMPLE + s] = (float)p;  // idx stored as float32
  float* g = out + OFF_GXYZ + (qs * NSAMPLE + s) * 3;
  g[0] = dx;
  g[1] = dy;
  g[2] = dz;
  const float* row = base + (size_t)p * CH;
  float4 r1 = *reinterpret_cast<const float4*>(row + 4);
  float4 r2 = *reinterpret_cast<const float4*>(row + 8);
  float4 r3 = *reinterpret_cast<const float4*>(row + 12);
  float* np_ = out + OFF_NEWPTS + (qs * NSAMPLE + s) * CH;
  *reinterpret_cast<float4*>(np_ + 0) = make_float4(dx, dy, dz, r0.w);
  *reinterpret_cast<float4*>(np_ + 4) = r1;
  *reinterpret_cast<float4*>(np_ + 8) = r2;
  *reinterpret_cast<float4*>(np_ + 12) = r3;
}

__global__ __launch_bounds__(256) void ballq_kernel(
    const float* __restrict__ in, float* __restrict__ out) {
  const int lane = threadIdx.x & 63;
  const int qid = blockIdx.x * 4 + (threadIdx.x >> 6);
  const int b = qid >> 11;    // / NPOINT
  const int qi = qid & 2047;  // % NPOINT
  const float* base = in + (size_t)b * NPTS * CH;
  const float* q = out + OFF_NEWXYZ + ((size_t)b * NPOINT + qi) * 3;
  float qx = q[0], qy = q[1], qz = q[2];
  // Mirror reference: d2 = sum(q*q) + sum(p*p) - 2*(q . p)
  float qn = __fadd_rn(__fadd_rn(__fmul_rn(qx, qx), __fmul_rn(qy, qy)),
                       __fmul_rn(qz, qz));

  int cnt = 0;
  int first = 0;
  bool have_first = false;
  for (int chunk = 0; chunk < NPTS / 64 && cnt < NSAMPLE; ++chunk) {
    int p = chunk * 64 + lane;
    float4 r0 = *reinterpret_cast<const float4*>(base + (size_t)p * CH);
    float pn =
        __fadd_rn(__fadd_rn(__fmul_rn(r0.x, r0.x), __fmul_rn(r0.y, r0.y)),
                  __fmul_rn(r0.z, r0.z));
    float dot =
        __fadd_rn(__fadd_rn(__fmul_rn(qx, r0.x), __fmul_rn(qy, r0.y)),
                  __fmul_rn(qz, r0.z));
    float d2 = __fsub_rn(__fadd_rn(qn, pn), __fmul_rn(2.0f, dot));
    bool in_r = d2 < 1.0f;  // RADIUS^2
    unsigned long long mask = __ballot(in_r);
    if (!have_first && mask) {
      first = chunk * 64 + __builtin_ctzll(mask);
      have_first = true;
    }
    int pos = cnt + __popcll(mask & ((1ull << lane) - 1ull));
    if (in_r && pos < NSAMPLE) write_slot(out, base, b, qi, pos, p, r0, qx, qy, qz);
    cnt += __popcll(mask);
  }
  if (cnt < NSAMPLE) {
    // Pad remaining slots with the first in-radius index (reference fill rule).
    int s = cnt + lane;
    if (s < NSAMPLE) {
      float4 r0 = *reinterpret_cast<const float4*>(base + (size_t)first * CH);
      write_slot(out, base, b, qi, s, first, r0, qx, qy, qz);
    }
  }
}

extern "C" void kernel_launch(void* const* d_in, const int* in_sizes, int n_in,
                              void* d_out, int out_size, void* d_ws,
                              size_t ws_size, hipStream_t stream) {
  (void)in_sizes;
  (void)n_in;
  (void)out_size;
  (void)d_ws;
  (void)ws_size;
  const float* in = (const float*)d_in[0];
  float* out = (float*)d_out;
  fps_kernel<<<NB, FPS_THREADS, 0, stream>>>(in, out);
  ballq_kernel<<<(NB * NPOINT) / 4, 256, 0, stream>>>(in, out);
}

// Round 10
// 2028.849 us; speedup vs baseline: 2.3395x; 1.0000x over previous
//
#include <hip/hip_runtime.h>

// File-scope: forbid implicit fma contraction everywhere (keeps every a*b+c
// as two single-rounded IEEE ops, matching the numpy reference bit-for-bit;
// explicit __f*_rn intrinsics below are unaffected).
#pragma clang fp contract(off)

#define NPOINT 2048
#define NSAMPLE 32
#define NPTS 8192
#define NB 4
#define CH 16
#define FPS_THREADS 1024
#define PTS_PER_THREAD (NPTS / FPS_THREADS) /* 8 */
#define PAIRS (PTS_PER_THREAD / 2)          /* 4 */
#define FPS_WAVES (FPS_THREADS / 64)        /* 16 */

typedef unsigned long long u64;
typedef float v2f __attribute__((ext_vector_type(2)));

// Output layout (flat float32, concatenated in reference return order)
#define OFF_NEWXYZ 0
#define OFF_NEWPTS (NB * NPOINT * 3)                          /* 24576 */
#define OFF_IDX (OFF_NEWPTS + NB * NPOINT * NSAMPLE * CH)     /* 4218880 */
#define OFF_GXYZ (OFF_IDX + NB * NPOINT * NSAMPLE)            /* 4481024 */

template <int CTRL>
__device__ __forceinline__ float dpp_fmax(float v) {
  // bound_ctrl=true -> 0-fill; distances are >= 0 so 0 is a safe identity.
  int o = __builtin_amdgcn_update_dpp(0, __float_as_int(v), CTRL, 0xf, 0xf, true);
  return fmaxf(v, __int_as_float(o));
}

// ---------------- FPS: one block per batch, sequential 2048-step scan ------
// Reference semantics: idxs[0]=0; each step: dists=min(dists,|p-p_last|^2),
// next = argmax(dists) with FIRST-index tie-break. Op order mirrored:
// (dx*dx + dy*dy) + dz*dz, single-rounded IEEE ops, no fma contraction
// (file-scope pragma). Packed v2f math has identical per-element rounding.
//
// R9 post-mortem: active-CU VALUBusy 82% at ~229 inst/wave/iter vs ~120
// static count -> allocator (default ~8 waves/EU target, 64-VGPR budget)
// parked the 32-float arrays in AGPRs and pays v_accvgpr_read/write on every
// access (VGPR_Count=52 can't hold arrays + working set). LDS (156 KB) already
// caps us at 1 block/CU = 4 waves/SIMD, so a 128-VGPR budget costs nothing:
// amdgpu_waves_per_eu(4,4) tells the allocator the truth.
__global__ __launch_bounds__(FPS_THREADS)
__attribute__((amdgpu_waves_per_eu(4, 4))) void fps_kernel(
    const float* __restrict__ in, float* __restrict__ out) {
  __shared__ float4 lpxyz[NPTS];      // 128 KB; winner coords: 1 ds_read_b128
  __shared__ float newb[NPOINT * 3];  // 24 KB newxyz staging
  __shared__ u64 slots[2][FPS_WAVES]; // low=dist bits, high=idx (per wave)

  const int b = blockIdx.x;
  const int tid = threadIdx.x;
  const int lane = tid & 63;
  const int wv = tid >> 6;
  const float* base = in + (size_t)b * NPTS * CH;

  v2f pxv[PAIRS], pyv[PAIRS], pzv[PAIRS], dv[PAIRS];
#pragma unroll
  for (int jp = 0; jp < PAIRS; ++jp) {
    int p0 = tid * PTS_PER_THREAD + 2 * jp;
    float4 r0 = *reinterpret_cast<const float4*>(base + (size_t)p0 * CH);
    float4 r1 = *reinterpret_cast<const float4*>(base + (size_t)(p0 + 1) * CH);
    pxv[jp] = (v2f){r0.x, r1.x};
    pyv[jp] = (v2f){r0.y, r1.y};
    pzv[jp] = (v2f){r0.z, r1.z};
    lpxyz[p0] = r0;
    lpxyz[p0 + 1] = r1;
    dv[jp] = (v2f){__builtin_inff(), __builtin_inff()};
  }
  // Prime parity-0 slots: slot 0 = (+inf, idx 0) wins the first reduce.
  if (tid < FPS_WAVES)
    slots[0][tid] = (tid == 0) ? (u64)0x7f800000u : (u64)0xbf800000u;

  for (int it = 0; it < NPOINT; ++it) {
    const int pb = it & 1;
    __syncthreads();
    // Cross-wave reduce: lane reads slot[lane&15] (2-way bank alias = free);
    // 4 f32 DPP row_shr max rounds -> every row's lane 15 = max of 16 slots;
    // ballot(own==max)&0xFFFF, ctz -> lowest wave (= lowest index range).
    u64 sl = slots[pb][lane & 15];
    float sd = __int_as_float((int)(unsigned)sl);
    int sidx = (int)(unsigned)(sl >> 32);
    float m = sd;
    m = dpp_fmax<0x111>(m);  // row_shr:1
    m = dpp_fmax<0x112>(m);  // row_shr:2
    m = dpp_fmax<0x114>(m);  // row_shr:4
    m = dpp_fmax<0x118>(m);  // row_shr:8
    const float smax =
        __int_as_float(__builtin_amdgcn_readlane(__float_as_int(m), 15));
    const u64 bal = __ballot(sd == smax) & 0xFFFFull;
    const int wwin = (int)__builtin_ctzll(bal);
    const int gi = __builtin_amdgcn_readlane(sidx, wwin);
    // Winner coords: broadcast LDS read (uniform SGPR address).
    float4 g = lpxyz[gi];
    const float gx = g.x, gy = g.y, gz = g.z;
    if (tid == 0) {
      newb[it * 3 + 0] = gx;
      newb[it * 3 + 1] = gy;
      newb[it * 3 + 2] = gz;
    }
    // Distance update (packed pairs; exact IEEE per-element, no contraction)
    // + value-only max.
    float bestv = -1.0f;
#pragma unroll
    for (int jp = 0; jp < PAIRS; ++jp) {
      v2f dx = pxv[jp] - gx;
      v2f dy = pyv[jp] - gy;
      v2f dz = pzv[jp] - gz;
      v2f nd = (dx * dx + dy * dy) + dz * dz;
      v2f dn = {fminf(dv[jp].x, nd.x), fminf(dv[jp].y, nd.y)};
      dv[jp] = dn;
      bestv = fmaxf(bestv, fmaxf(dn.x, dn.y));
    }
    // Recover lowest j achieving bestv (descending scan -> lowest wins).
    const float* df = (const float*)dv;
    int bestj = 0;
#pragma unroll
    for (int jj = PTS_PER_THREAD - 1; jj >= 0; --jj)
      if (df[jj] == bestv) bestj = jj;
    const int besti = tid * PTS_PER_THREAD + bestj;
    // Wave reduce: f32 DPP max -> lane 63; ballot picks lowest lane (= lowest
    // index under contiguous ownership); readlane pulls its index.
    float wm = bestv;
    wm = dpp_fmax<0x111>(wm);  // row_shr:1
    wm = dpp_fmax<0x112>(wm);  // row_shr:2
    wm = dpp_fmax<0x114>(wm);  // row_shr:4
    wm = dpp_fmax<0x118>(wm);  // row_shr:8
    wm = dpp_fmax<0x142>(wm);  // row_bcast15
    wm = dpp_fmax<0x143>(wm);  // row_bcast31
    const float swm =
        __int_as_float(__builtin_amdgcn_readlane(__float_as_int(wm), 63));
    const u64 wbal = __ballot(bestv == swm);
    const int wl = (int)__builtin_ctzll(wbal);
    const int widx = __builtin_amdgcn_readlane(besti, wl);
    if (lane == 0)
      slots[pb ^ 1][wv] =
          ((u64)(unsigned)widx << 32) | (unsigned)__float_as_int(swm);
  }
  __syncthreads();
  // Dump staged newxyz to global once.
  float* ob = out + OFF_NEWXYZ + (size_t)b * NPOINT * 3;
  for (int i = tid; i < NPOINT * 3; i += FPS_THREADS) ob[i] = newb[i];
}

// ---------------- Ball query + group: one wave per query -------------------
__device__ __forceinline__ void write_slot(float* __restrict__ out,
                                           const float* __restrict__ base,
                                           int b, int qi, int s, int p,
                                           float4 r0, float qx, float qy,
                                           float qz) {
  float dx = __fsub_rn(r0.x, qx);
  float dy = __fsub_rn(r0.y, qy);
  float dz = __fsub_rn(r0.z, qz);
  size_t qs = (size_t)b * NPOINT + qi;
  out[OFF_IDX + qs * NSAMPLE + s] = (float)p;  // idx stored as float32
  float* g = out + OFF_GXYZ + (qs * NSAMPLE + s) * 3;
  g[0] = dx;
  g[1] = dy;
  g[2] = dz;
  const float* row = base + (size_t)p * CH;
  float4 r1 = *reinterpret_cast<const float4*>(row + 4);
  float4 r2 = *reinterpret_cast<const float4*>(row + 8);
  float4 r3 = *reinterpret_cast<const float4*>(row + 12);
  float* np_ = out + OFF_NEWPTS + (qs * NSAMPLE + s) * CH;
  *reinterpret_cast<float4*>(np_ + 0) = make_float4(dx, dy, dz, r0.w);
  *reinterpret_cast<float4*>(np_ + 4) = r1;
  *reinterpret_cast<float4*>(np_ + 8) = r2;
  *reinterpret_cast<float4*>(np_ + 12) = r3;
}

__global__ __launch_bounds__(256) void ballq_kernel(
    const float* __restrict__ in, float* __restrict__ out) {
  const int lane = threadIdx.x & 63;
  const int qid = blockIdx.x * 4 + (threadIdx.x >> 6);
  const int b = qid >> 11;    // / NPOINT
  const int qi = qid & 2047;  // % NPOINT
  const float* base = in + (size_t)b * NPTS * CH;
  const float* q = out + OFF_NEWXYZ + ((size_t)b * NPOINT + qi) * 3;
  float qx = q[0], qy = q[1], qz = q[2];
  // Mirror reference: d2 = sum(q*q) + sum(p*p) - 2*(q . p)
  float qn = __fadd_rn(__fadd_rn(__fmul_rn(qx, qx), __fmul_rn(qy, qy)),
                       __fmul_rn(qz, qz));

  int cnt = 0;
  int first = 0;
  bool have_first = false;
  for (int chunk = 0; chunk < NPTS / 64 && cnt < NSAMPLE; ++chunk) {
    int p = chunk * 64 + lane;
    float4 r0 = *reinterpret_cast<const float4*>(base + (size_t)p * CH);
    float pn =
        __fadd_rn(__fadd_rn(__fmul_rn(r0.x, r0.x), __fmul_rn(r0.y, r0.y)),
                  __fmul_rn(r0.z, r0.z));
    float dot =
        __fadd_rn(__fadd_rn(__fmul_rn(qx, r0.x), __fmul_rn(qy, r0.y)),
                  __fmul_rn(qz, r0.z));
    float d2 = __fsub_rn(__fadd_rn(qn, pn), __fmul_rn(2.0f, dot));
    bool in_r = d2 < 1.0f;  // RADIUS^2
    unsigned long long mask = __ballot(in_r);
    if (!have_first && mask) {
      first = chunk * 64 + __builtin_ctzll(mask);
      have_first = true;
    }
    int pos = cnt + __popcll(mask & ((1ull << lane) - 1ull));
    if (in_r && pos < NSAMPLE) write_slot(out, base, b, qi, pos, p, r0, qx, qy, qz);
    cnt += __popcll(mask);
  }
  if (cnt < NSAMPLE) {
    // Pad remaining slots with the first in-radius index (reference fill rule).
    int s = cnt + lane;
    if (s < NSAMPLE) {
      float4 r0 = *reinterpret_cast<const float4*>(base + (size_t)first * CH);
      write_slot(out, base, b, qi, s, first, r0, qx, qy, qz);
    }
  }
}

extern "C" void kernel_launch(void* const* d_in, const int* in_sizes, int n_in,
                              void* d_out, int out_size, void* d_ws,
                              size_t ws_size, hipStream_t stream) {
  (void)in_sizes;
  (void)n_in;
  (void)out_size;
  (void)d_ws;
  (void)ws_size;
  const float* in = (const float*)d_in[0];
  float* out = (float*)d_out;
  fps_kernel<<<NB, FPS_THREADS, 0, stream>>>(in, out);
  ballq_kernel<<<(NB * NPOINT) / 4, 256, 0, stream>>>(in, out);
}